// Round 1
// baseline (468.822 us; speedup 1.0000x reference)
//
#include <hip/hip_runtime.h>
#include <stdint.h>
#include <math.h>

typedef unsigned short u16;
typedef __attribute__((ext_vector_type(8))) short short8;
typedef __attribute__((ext_vector_type(4))) float f32x4;

__device__ __forceinline__ float bf2f(u16 u){
  union { unsigned int i; float f; } v; v.i = ((unsigned int)u) << 16; return v.f;
}
__device__ __forceinline__ u16 f2bf(float f){
  union { float f; unsigned int i; } v; v.f = f;
  return (u16)((v.i + 0x7FFFu + ((v.i >> 16) & 1u)) >> 16);
}

// ---------------- LayerNorm + x->bf16 (one row per block) ----------------
__global__ void ln_prep(const float* __restrict__ x, const float* __restrict__ g,
                        const float* __restrict__ bta, u16* __restrict__ h,
                        u16* __restrict__ xb, float* __restrict__ loss){
  if (blockIdx.x == 0 && threadIdx.x == 0) loss[0] = 0.f;
  int row = blockIdx.x, tid = threadIdx.x;
  const float4* xr = (const float4*)(x + (size_t)row * 1024);
  float4 v = xr[tid];
  float s  = v.x + v.y + v.z + v.w;
  float s2 = v.x*v.x + v.y*v.y + v.z*v.z + v.w*v.w;
  #pragma unroll
  for (int o = 32; o > 0; o >>= 1){ s += __shfl_down(s, o); s2 += __shfl_down(s2, o); }
  __shared__ float red[8];
  if ((tid & 63) == 0){ red[tid >> 6] = s; red[4 + (tid >> 6)] = s2; }
  __syncthreads();
  float ts = red[0]+red[1]+red[2]+red[3];
  float t2 = red[4]+red[5]+red[6]+red[7];
  float mu   = ts * (1.0f/1024.0f);
  float var  = t2 * (1.0f/1024.0f) - mu*mu;
  float rstd = rsqrtf(var + 1e-5f);
  float4 gg = ((const float4*)g)[tid];
  float4 bb = ((const float4*)bta)[tid];
  ushort4 hv, xv;
  hv.x = f2bf((v.x-mu)*rstd*gg.x + bb.x);
  hv.y = f2bf((v.y-mu)*rstd*gg.y + bb.y);
  hv.z = f2bf((v.z-mu)*rstd*gg.z + bb.z);
  hv.w = f2bf((v.w-mu)*rstd*gg.w + bb.w);
  xv.x = f2bf(v.x); xv.y = f2bf(v.y); xv.z = f2bf(v.z); xv.w = f2bf(v.w);
  ((ushort4*)h )[(size_t)row*256 + tid] = hv;
  ((ushort4*)xb)[(size_t)row*256 + tid] = xv;
}

// ---------------- fp32 -> bf16 weight conversion (5 matrices) ----------------
__global__ void conv5(const float* __restrict__ a, const float* __restrict__ b,
                      const float* __restrict__ c, const float* __restrict__ d,
                      const float* __restrict__ e,
                      u16* oa, u16* ob, u16* oc, u16* od, u16* oe){
  int sel = blockIdx.y;
  const float* s = sel==0?a : sel==1?b : sel==2?c : sel==3?d : e;
  u16* o = sel==0?oa : sel==1?ob : sel==2?oc : sel==3?od : oe;
  int i = blockIdx.x*256 + threadIdx.x;   // 262144 float4's
  float4 v = ((const float4*)s)[i];
  ushort4 r; r.x=f2bf(v.x); r.y=f2bf(v.y); r.z=f2bf(v.z); r.w=f2bf(v.w);
  ((ushort4*)o)[i] = r;
}

// --------- WeffT[d][e] = W0[e][d] + sum_r A[e][r]*B[r][d], bf16 out ---------
__global__ void weff_k(const float* __restrict__ W0, const float* __restrict__ Ai,
                       const float* __restrict__ Bi, u16* __restrict__ Wet){
  __shared__ float tile[32][33];
  int d0 = blockIdx.x*32, e0 = blockIdx.y*32;
  int tid = threadIdx.x;
  int lr = tid >> 5, lc = tid & 31;
  #pragma unroll
  for (int s = 0; s < 4; ++s){
    int e = e0 + s*8 + lr, d = d0 + lc;
    float v = W0[(size_t)e*1024 + d];
    #pragma unroll
    for (int r = 0; r < 8; ++r) v += Ai[e*8 + r] * Bi[(size_t)r*1024 + d];
    tile[s*8 + lr][lc] = v;
  }
  __syncthreads();
  #pragma unroll
  for (int s = 0; s < 4; ++s){
    int d = d0 + s*8 + lr, e = e0 + lc;
    Wet[(size_t)d*1024 + e] = f2bf(tile[lc][s*8 + lr]);
  }
}

// ---------------- MFMA GEMM: C[m,n] = sum_k A[m,k]*Bm[n,k]  (K=1024) --------
// 128x128 tile, BK=64, 256 thr = 4 waves (2x2), each wave 4x4 of 16x16x32.
template<int EPI>
__device__ __forceinline__ void gemm_body(const u16* __restrict__ A, const u16* __restrict__ Bm,
    u16* __restrict__ Cb, float* __restrict__ Cf, const float* __restrict__ lsg,
    const float* __restrict__ xres, int mblk, int nblk){
  __shared__ u16 As[128*64];
  __shared__ u16 Bs[128*64];
  const int tid  = threadIdx.x;
  const int lane = tid & 63;
  const int w    = tid >> 6;
  const int m0 = mblk * 128, n0 = nblk * 128;
  const int lrow = lane >> 3, lcol8 = (lane & 7) * 8;
  const int wm = w & 1, wn = w >> 1;
  const int l15 = lane & 15, quad = lane >> 4;

  f32x4 acc[4][4] = {};

  #pragma unroll 1
  for (int kk = 0; kk < 1024; kk += 64){
    #pragma unroll
    for (int it = 0; it < 4; ++it){
      int r0 = w*8 + it*32;
      const u16* ga = A  + (size_t)(m0 + r0 + lrow)*1024 + kk + lcol8;
      __builtin_amdgcn_global_load_lds((const __attribute__((address_space(1))) unsigned int*)ga,
          (__attribute__((address_space(3))) unsigned int*)(As + r0*64), 16, 0, 0);
      const u16* gb = Bm + (size_t)(n0 + r0 + lrow)*1024 + kk + lcol8;
      __builtin_amdgcn_global_load_lds((const __attribute__((address_space(1))) unsigned int*)gb,
          (__attribute__((address_space(3))) unsigned int*)(Bs + r0*64), 16, 0, 0);
    }
    __syncthreads();
    #pragma unroll
    for (int kh = 0; kh < 2; ++kh){
      int kb = kh*32 + quad*8;
      short8 af[4], bfv[4];
      #pragma unroll
      for (int i = 0; i < 4; ++i) af[i]  = *(const short8*)(As + (wm*64 + i*16 + l15)*64 + kb);
      #pragma unroll
      for (int j = 0; j < 4; ++j) bfv[j] = *(const short8*)(Bs + (wn*64 + j*16 + l15)*64 + kb);
      #pragma unroll
      for (int i = 0; i < 4; ++i)
        #pragma unroll
        for (int j = 0; j < 4; ++j)
          acc[i][j] = __builtin_amdgcn_mfma_f32_16x16x32_bf16(af[i], bfv[j], acc[i][j], 0, 0, 0);
    }
    __syncthreads();
  }

  const int rbase = quad * 4;
  if (EPI == 0){
    #pragma unroll
    for (int i = 0; i < 4; ++i){
      int row = m0 + wm*64 + i*16 + rbase;
      #pragma unroll
      for (int j = 0; j < 4; ++j){
        int col = n0 + wn*64 + j*16 + l15;
        #pragma unroll
        for (int r = 0; r < 4; ++r)
          Cb[(size_t)(row + r)*1024 + col] = f2bf(acc[i][j][r]);
      }
    }
  } else {
    float lsv[4];
    #pragma unroll
    for (int j = 0; j < 4; ++j) lsv[j] = lsg[n0 + wn*64 + j*16 + l15];
    #pragma unroll
    for (int i = 0; i < 4; ++i){
      int row = m0 + wm*64 + i*16 + rbase;
      #pragma unroll
      for (int j = 0; j < 4; ++j){
        int col = n0 + wn*64 + j*16 + l15;
        #pragma unroll
        for (int r = 0; r < 4; ++r){
          size_t idx = (size_t)(row + r)*1024 + col;
          Cf[idx] = acc[i][j][r] * lsv[j] + xres[idx];
        }
      }
    }
  }
}

// fused Q/K/V/Gate GEMM: grid (128, 32); blockIdx.y>>3 selects output
__global__ void gemm_qkvg(const u16* __restrict__ h, const u16* __restrict__ xb,
                          const u16* __restrict__ Wqb, const u16* __restrict__ Wkb,
                          const u16* __restrict__ Wvb, const u16* __restrict__ Wgb,
                          u16* __restrict__ Qb, u16* __restrict__ Kb,
                          u16* __restrict__ Vb, u16* __restrict__ Gb){
  int sel = blockIdx.y >> 3;
  const u16* A  = (sel == 3) ? xb : h;
  const u16* Bm = sel==0?Wqb : sel==1?Wkb : sel==2?Wvb : Wgb;
  u16* Out      = sel==0?Qb  : sel==1?Kb  : sel==2?Vb  : Gb;
  gemm_body<0>(A, Bm, Out, nullptr, nullptr, nullptr, blockIdx.x, blockIdx.y & 7);
}

__global__ void gemm_plain(const u16* __restrict__ A, const u16* __restrict__ Bm,
                           u16* __restrict__ C){
  gemm_body<0>(A, Bm, C, nullptr, nullptr, nullptr, blockIdx.x, blockIdx.y);
}

__global__ void gemm_final(const u16* __restrict__ A, const u16* __restrict__ Bm,
                           float* __restrict__ C, const float* __restrict__ lsg,
                           const float* __restrict__ xres){
  gemm_body<1>(A, Bm, nullptr, C, lsg, xres, blockIdx.x, blockIdx.y);
}

// ---------------- scan pass 1: per-chunk gradient sums + loss ----------------
// grid (4, 32, 4): (c-block, chunk, batch); chunk = 128 timesteps
__global__ void scan1(const u16* __restrict__ Kb, const u16* __restrict__ Vb,
                      const u16* __restrict__ Yb, float* __restrict__ part,
                      float* __restrict__ loss){
  int tid = threadIdx.x;
  int c = blockIdx.x*256 + tid;
  int ch = blockIdx.y, b = blockIdx.z;
  size_t base = ((size_t)b*4096 + (size_t)ch*128)*1024 + c;
  float g = 0.f, ls = 0.f;
  #pragma unroll 8
  for (int t = 0; t < 128; ++t){
    size_t idx = base + (size_t)t*1024;
    float kv = bf2f(Kb[idx]), vv = bf2f(Vb[idx]), yv = bf2f(Yb[idx]);
    float e = yv - vv;
    g += kv*e; ls += e*e;
  }
  part[((size_t)(b*32 + ch))*1024 + c] = g;
  #pragma unroll
  for (int o = 32; o > 0; o >>= 1) ls += __shfl_down(ls, o);
  __shared__ float red[4];
  if ((tid & 63) == 0) red[tid >> 6] = ls;
  __syncthreads();
  if (tid == 0) atomicAdd(loss, red[0]+red[1]+red[2]+red[3]);
}

// -------- scan pass 2: out_pre = (y0 - Q*lr*shift*pos_scale)*sigmoid(G) ------
__global__ void scan2(const u16* __restrict__ Kb, const u16* __restrict__ Vb,
                      const u16* __restrict__ Yb, const u16* __restrict__ Qb,
                      const u16* __restrict__ Gb, const float* __restrict__ part,
                      const float* __restrict__ llr, u16* __restrict__ OutPre){
  int tid = threadIdx.x;
  int c = blockIdx.x*256 + tid;
  int ch = blockIdx.y, b = blockIdx.z;
  float run = 0.f;
  for (int j = 0; j < ch; ++j) run += part[((size_t)(b*32 + j))*1024 + c];
  float lrc = fminf(expf(llr[c]), 1.0f);
  size_t base = ((size_t)b*4096 + (size_t)ch*128)*1024 + c;
  #pragma unroll 4
  for (int t = 0; t < 128; ++t){
    size_t idx = base + (size_t)t*1024;
    float kv = bf2f(Kb[idx]), vv = bf2f(Vb[idx]), yv = bf2f(Yb[idx]);
    float qv = bf2f(Qb[idx]), gl = bf2f(Gb[idx]);
    float e = yv - vv;
    int tg = ch*128 + t + 1;
    float ps = 1.0f/(1.0f + 0.1f*logf((float)tg));
    float gate = 1.0f/(1.0f + expf(-gl));
    float o = (yv - qv*lrc*run*ps) * gate;
    OutPre[idx] = f2bf(o);     // same buffer as Qb: read-before-write per element
    run += kv*e;
  }
}

__global__ void finloss(const float* __restrict__ loss, float* __restrict__ o){
  o[0] = loss[0] * (1.0f/16777216.0f);
}

extern "C" void kernel_launch(void* const* d_in, const int* in_sizes, int n_in,
                              void* d_out, int out_size, void* d_ws, size_t ws_size,
                              hipStream_t stream){
  const float* x   = (const float*)d_in[0];
  const float* W0  = (const float*)d_in[1];
  const float* Ai  = (const float*)d_in[2];
  const float* Bi  = (const float*)d_in[3];
  const float* llr = (const float*)d_in[4];
  const float* Wq  = (const float*)d_in[5];
  const float* Wk  = (const float*)d_in[6];
  const float* Wv  = (const float*)d_in[7];
  const float* Wo  = (const float*)d_in[8];
  const float* Wg  = (const float*)d_in[9];
  const float* lng = (const float*)d_in[10];
  const float* lnb = (const float*)d_in[11];
  const float* lsg = (const float*)d_in[12];
  float* out = (float*)d_out;

  const size_t TOK = 16384, CC = 1024;
  char* p = (char*)d_ws;
  float* loss = (float*)p; p += 256;
  u16* h   = (u16*)p; p += TOK*CC*2;   // reused as y0 after GEMM1
  u16* xb  = (u16*)p; p += TOK*CC*2;
  u16* Qb  = (u16*)p; p += TOK*CC*2;   // reused as out_pre in scan2
  u16* Kb  = (u16*)p; p += TOK*CC*2;
  u16* Vb  = (u16*)p; p += TOK*CC*2;
  u16* Gb  = (u16*)p; p += TOK*CC*2;
  u16* Wqb = (u16*)p; p += CC*CC*2;
  u16* Wkb = (u16*)p; p += CC*CC*2;
  u16* Wvb = (u16*)p; p += CC*CC*2;
  u16* Wgb = (u16*)p; p += CC*CC*2;
  u16* Wob = (u16*)p; p += CC*CC*2;
  u16* Wet = (u16*)p; p += CC*CC*2;
  float* part = (float*)p; p += (size_t)4*32*1024*4;

  ln_prep<<<16384, 256, 0, stream>>>(x, lng, lnb, h, xb, loss);
  conv5<<<dim3(1024, 5), 256, 0, stream>>>(Wq, Wk, Wv, Wg, Wo, Wqb, Wkb, Wvb, Wgb, Wob);
  weff_k<<<dim3(32, 32), 256, 0, stream>>>(W0, Ai, Bi, Wet);
  gemm_qkvg<<<dim3(128, 32), 256, 0, stream>>>(h, xb, Wqb, Wkb, Wvb, Wgb, Qb, Kb, Vb, Gb);
  gemm_plain<<<dim3(128, 8), 256, 0, stream>>>(Kb, Wet, h);                 // y0 -> h buffer
  scan1<<<dim3(4, 32, 4), 256, 0, stream>>>(Kb, Vb, h, part, loss);
  scan2<<<dim3(4, 32, 4), 256, 0, stream>>>(Kb, Vb, h, Qb, Gb, part, llr, Qb);
  gemm_final<<<dim3(128, 8), 256, 0, stream>>>(Qb, Wob, out, lsg, x);
  finloss<<<1, 1, 0, stream>>>(loss, out + 16777216);
}